// Round 2
// baseline (95.495 us; speedup 1.0000x reference)
//
#include <hip/hip_runtime.h>
#include <math.h>

// PartialChamferLoss: B=2, N=8192, M=32768, S=4096.
// d2 = |x|^2 + |y|^2 - 2 x.y ; min over M per query ; mean(sqrt).
// Strategy: targets register-resident (R=16 float4/lane = 1024/wave),
// queries + running min rotate around the wave via __shfl. 5 VALU ops/pair.
constexpr int B = 2;
constexpr int N = 8192;
constexpr int M = 32768;
constexpr int S = 4096;
constexpr int QTOT = B * S;          // 8192 queries
constexpr int R = 16;                // targets per lane
constexpr int WT = 64 * R;           // 1024 targets per wave
constexpr int TCH = M / WT;          // 32 target chunks per batch
constexpr int QG = S / 64;           // 64 query groups per batch
constexpr int WAVES = B * TCH * QG;  // 4096 waves
constexpr int BLOCKS = WAVES / 4;    // 1024 blocks x 256 threads

// ws layout: [0, 32KB)  : 8192 u32 min-bits (init +inf)
//            [32KB, 160KB): 8192 float4 query records (-2x,-2y,-2z,|x|^2)

__global__ __launch_bounds__(256) void chamfer_prep(
    const float* __restrict__ pred, const int* __restrict__ idx,
    float4* __restrict__ qrec, unsigned* __restrict__ wsmin) {
  int q = blockIdx.x * 256 + threadIdx.x;
  if (q >= QTOT) return;
  int b = q / S;
  int s = q - b * S;
  int i = idx[s];
  const float* p = pred + ((size_t)b * N + (size_t)i) * 3;
  float x = p[0], y = p[1], z = p[2];
  qrec[q] = make_float4(-2.0f * x, -2.0f * y, -2.0f * z,
                        x * x + y * y + z * z);
  wsmin[q] = 0x7F800000u;  // +inf bits (atomicMin on uint == float min for >=0)
}

__global__ __launch_bounds__(256) void chamfer_main(
    const float* __restrict__ target, const float4* __restrict__ qrec,
    unsigned* __restrict__ wsmin) {
  const int lane = threadIdx.x & 63;
  const int w = blockIdx.x * 4 + (threadIdx.x >> 6);  // 0..4095
  const int b = w >> 11;                              // / (TCH*QG)
  const int rem = w & 2047;
  const int tch = rem & (TCH - 1);
  const int qg = rem >> 5;                            // / TCH

  // Stage this lane's 16 targets into registers (coalesced 12B/lane reads).
  const float* tb = target + ((size_t)b * M + (size_t)tch * WT) * 3;
  float t0[R], t1[R], t2[R], ty2[R];
#pragma unroll
  for (int j = 0; j < R; ++j) {
    int m = j * 64 + lane;
    float a = tb[3 * m + 0];
    float c = tb[3 * m + 1];
    float d = tb[3 * m + 2];
    t0[j] = a; t1[j] = c; t2[j] = d;
    ty2[j] = fmaf(a, a, fmaf(c, c, d * d));
  }

  const int q = b * S + qg * 64 + lane;
  float4 qr = qrec[q];
  float q0 = qr.x, q1 = qr.y, q2 = qr.z, qx2 = qr.w;
  float m0 = INFINITY, m1 = INFINITY;  // 2 accumulators: shorter dep chain

  for (int step = 0; step < 64; ++step) {
#pragma unroll
    for (int j = 0; j < R; j += 2) {
      float s0 = qx2 + ty2[j];
      s0 = fmaf(q0, t0[j], s0);
      s0 = fmaf(q1, t1[j], s0);
      s0 = fmaf(q2, t2[j], s0);
      m0 = fminf(m0, s0);
      float s1 = qx2 + ty2[j + 1];
      s1 = fmaf(q0, t0[j + 1], s1);
      s1 = fmaf(q1, t1[j + 1], s1);
      s1 = fmaf(q2, t2[j + 1], s1);
      m1 = fminf(m1, s1);
    }
    float mm = fminf(m0, m1);
    // Rotate query record + its running min one lane down; after 64 steps
    // each query has visited every lane's targets and is back home.
    int src = (lane + 1) & 63;
    q0 = __shfl(q0, src);
    q1 = __shfl(q1, src);
    q2 = __shfl(q2, src);
    qx2 = __shfl(qx2, src);
    mm = __shfl(mm, src);
    m0 = mm;
    m1 = INFINITY;
  }
  float mm = fminf(m0, m1);
  mm = fmaxf(mm, 0.0f);  // reference clamps d2 at 0; also required for uint-min
  atomicMin(&wsmin[q], __float_as_uint(mm));
}

__global__ __launch_bounds__(256) void chamfer_finish(
    const unsigned* __restrict__ wsmin, float* __restrict__ out) {
  float sum = 0.0f;
  for (int q = threadIdx.x; q < QTOT; q += 256)
    sum += sqrtf(__uint_as_float(wsmin[q]));
#pragma unroll
  for (int off = 32; off > 0; off >>= 1)
    sum += __shfl_down(sum, off, 64);
  __shared__ float red[4];
  int wv = threadIdx.x >> 6;
  if ((threadIdx.x & 63) == 0) red[wv] = sum;
  __syncthreads();
  if (threadIdx.x == 0) {
    out[0] = (red[0] + red[1] + red[2] + red[3]) / (float)QTOT;
  }
}

extern "C" void kernel_launch(void* const* d_in, const int* in_sizes, int n_in,
                              void* d_out, int out_size, void* d_ws, size_t ws_size,
                              hipStream_t stream) {
  const float* pred = (const float*)d_in[0];
  const float* target = (const float*)d_in[1];
  const int* idx = (const int*)d_in[2];
  unsigned* wsmin = (unsigned*)d_ws;
  float4* qrec = (float4*)((char*)d_ws + 32 * 1024);

  chamfer_prep<<<QTOT / 256, 256, 0, stream>>>(pred, idx, qrec, wsmin);
  chamfer_main<<<BLOCKS, 256, 0, stream>>>(target, qrec, wsmin);
  chamfer_finish<<<1, 256, 0, stream>>>(wsmin, (float*)d_out);
}

// Round 3
// 84.498 us; speedup vs baseline: 1.1301x; 1.1301x over previous
//
#include <hip/hip_runtime.h>
#include <math.h>

// PartialChamferLoss: B=2, N=8192, M=32768, S=4096.
// d2 = |x|^2 + |y|^2 - 2 x.y ; min over M per query ; mean(sqrt).
// R3: |x|^2 folded out of inner loop (4 ops/pair), targets paired into
// float2 for v_pk_fma_f32 + v_min3_f32 (~2 inst/pair), query records read
// from a shared 1KB LDS ring (ds_read_b128) instead of 4 bpermutes/step;
// only the traveling min rotates via ds_bpermute.
typedef float vf2 __attribute__((ext_vector_type(2)));

constexpr int B = 2;
constexpr int N = 8192;
constexpr int M = 32768;
constexpr int S = 4096;
constexpr int QTOT = B * S;          // 8192 queries
constexpr int R = 16;                // targets per lane
constexpr int WT = 64 * R;           // 1024 targets per wave
constexpr int TCH = M / WT;          // 32 target chunks per batch
constexpr int QG = S / 64;           // 64 query groups per batch
constexpr int WAVES = B * TCH * QG;  // 4096 waves
constexpr int BLOCKS = WAVES / 4;    // 1024 blocks x 256 threads

// ws layout: [0, 32KB)   : 8192 u32 min-bits (init +inf)
//            [32KB,160KB): 8192 float4 query records (-2x,-2y,-2z,|x|^2)

__global__ __launch_bounds__(256) void chamfer_prep(
    const float* __restrict__ pred, const int* __restrict__ idx,
    float4* __restrict__ qrec, unsigned* __restrict__ wsmin) {
  int q = blockIdx.x * 256 + threadIdx.x;
  if (q >= QTOT) return;
  int b = q / S;
  int s = q - b * S;
  int i = idx[s];
  const float* p = pred + ((size_t)b * N + (size_t)i) * 3;
  float x = p[0], y = p[1], z = p[2];
  qrec[q] = make_float4(-2.0f * x, -2.0f * y, -2.0f * z,
                        x * x + y * y + z * z);
  wsmin[q] = 0x7F800000u;  // +inf bits (uint atomicMin == float min for >=0)
}

__global__ __launch_bounds__(256) void chamfer_main(
    const float* __restrict__ target, const float4* __restrict__ qrec,
    unsigned* __restrict__ wsmin) {
  __shared__ float4 qs[64];  // this block's query group (all 4 waves share qg)
  const int lane = threadIdx.x & 63;
  const int w = blockIdx.x * 4 + (threadIdx.x >> 6);  // 0..4095
  const int b = w >> 11;
  const int rem = w & 2047;
  const int tch = rem & (TCH - 1);
  const int qg = rem >> 5;  // uniform across the block's 4 waves

  if (threadIdx.x < 64)
    qs[threadIdx.x] = qrec[b * S + qg * 64 + threadIdx.x];

  // Stage this lane's 16 targets as 8 float2-pairs (pk_fma operands).
  const float* tb = target + ((size_t)b * M + (size_t)tch * WT) * 3;
  vf2 t0p[8], t1p[8], t2p[8], ty2p[8];
#pragma unroll
  for (int p = 0; p < 8; ++p) {
    int mA = (2 * p) * 64 + lane;
    int mB = (2 * p + 1) * 64 + lane;
    float ax = tb[3 * mA], ay = tb[3 * mA + 1], az = tb[3 * mA + 2];
    float bx = tb[3 * mB], by = tb[3 * mB + 1], bz = tb[3 * mB + 2];
    t0p[p] = vf2{ax, bx};
    t1p[p] = vf2{ay, by};
    t2p[p] = vf2{az, bz};
    ty2p[p] = vf2{fmaf(ax, ax, fmaf(ay, ay, az * az)),
                  fmaf(bx, bx, fmaf(by, by, bz * bz))};
  }
  __syncthreads();

  const float qx2_home = qs[lane].w;      // own |x|^2, applied at the end
  const int rot = ((lane + 1) & 63) * 4;  // bpermute byte-addr: pull lane+1
  float mm = INFINITY;                    // traveling min of (|y|^2 - 2x.y)
  int qoff = lane;                        // query slot this lane handles now

  for (int step = 0; step < 64; ++step) {
    float4 qr = qs[qoff];  // ds_read_b128, conflict-free rotation
    vf2 q0 = vf2{qr.x, qr.x}, q1 = vf2{qr.y, qr.y}, q2 = vf2{qr.z, qr.z};
    float m0 = mm, m1 = INFINITY;
#pragma unroll
    for (int p = 0; p < 8; p += 2) {
      vf2 s = __builtin_elementwise_fma(q0, t0p[p], ty2p[p]);
      s = __builtin_elementwise_fma(q1, t1p[p], s);
      s = __builtin_elementwise_fma(q2, t2p[p], s);
      m0 = fminf(fminf(s.x, s.y), m0);  // v_min3_f32
      vf2 u = __builtin_elementwise_fma(q0, t0p[p + 1], ty2p[p + 1]);
      u = __builtin_elementwise_fma(q1, t1p[p + 1], u);
      u = __builtin_elementwise_fma(q2, t2p[p + 1], u);
      m1 = fminf(fminf(u.x, u.y), m1);
    }
    mm = fminf(m0, m1);
    // Traveling min follows its query to the previous lane.
    mm = __int_as_float(__builtin_amdgcn_ds_bpermute(rot, __float_as_int(mm)));
    qoff = (qoff + 1) & 63;
  }
  // After 64 rotations the own query's complete min is back home.
  const int q = b * S + qg * 64 + lane;
  atomicMin(&wsmin[q], __float_as_uint(fmaxf(qx2_home + mm, 0.0f)));
}

__global__ __launch_bounds__(1024) void chamfer_finish(
    const unsigned* __restrict__ wsmin, float* __restrict__ out) {
  __shared__ float red[16];
  float sum = 0.0f;
  for (int q = threadIdx.x; q < QTOT; q += 1024)
    sum += sqrtf(__uint_as_float(wsmin[q]));
#pragma unroll
  for (int off = 32; off > 0; off >>= 1)
    sum += __shfl_down(sum, off, 64);
  int wv = threadIdx.x >> 6;
  if ((threadIdx.x & 63) == 0) red[wv] = sum;
  __syncthreads();
  if (threadIdx.x == 0) {
    float t = 0.0f;
#pragma unroll
    for (int i = 0; i < 16; ++i) t += red[i];
    out[0] = t / (float)QTOT;
  }
}

extern "C" void kernel_launch(void* const* d_in, const int* in_sizes, int n_in,
                              void* d_out, int out_size, void* d_ws, size_t ws_size,
                              hipStream_t stream) {
  const float* pred = (const float*)d_in[0];
  const float* target = (const float*)d_in[1];
  const int* idx = (const int*)d_in[2];
  unsigned* wsmin = (unsigned*)d_ws;
  float4* qrec = (float4*)((char*)d_ws + 32 * 1024);

  chamfer_prep<<<QTOT / 256, 256, 0, stream>>>(pred, idx, qrec, wsmin);
  chamfer_main<<<BLOCKS, 256, 0, stream>>>(target, qrec, wsmin);
  chamfer_finish<<<1, 1024, 0, stream>>>(wsmin, (float*)d_out);
}

// Round 4
// 83.471 us; speedup vs baseline: 1.1440x; 1.0123x over previous
//
#include <hip/hip_runtime.h>
#include <math.h>

// PartialChamferLoss: B=2, N=8192, M=32768, S=4096.
// d2 = |x|^2 + |y|^2 - 2 x.y ; min over M per query ; mean(sqrt).
// R4: R=32 targets/lane (2048/wave) halves LDS rotation traffic per CU ->
// VALU-bound; SoA query arrays in LDS (4B stride, conflict-free); prep fused
// into main (per-block gather, L2-hot); wsmin init via hipMemsetAsync(0x7F)
// (0x7F7F7F7F = 3.4e38 as float, > any d2; uint atomicMin order-safe >=0).
typedef float vf2 __attribute__((ext_vector_type(2)));

constexpr int B = 2;
constexpr int N = 8192;
constexpr int M = 32768;
constexpr int S = 4096;
constexpr int QTOT = B * S;          // 8192 queries
constexpr int R = 32;                // targets per lane
constexpr int WT = 64 * R;           // 2048 targets per wave
constexpr int TCH = M / WT;          // 16 target chunks per batch
constexpr int QG = S / 64;           // 64 query groups per batch
constexpr int WAVES = B * TCH * QG;  // 2048 waves
constexpr int BLOCKS = WAVES / 4;    // 512 blocks x 256 threads

// ws layout: [0, 32KB): 8192 u32 min-bits (memset 0x7F before main)

__global__ __launch_bounds__(256, 2) void chamfer_main(
    const float* __restrict__ pred, const float* __restrict__ target,
    const int* __restrict__ idx, unsigned* __restrict__ wsmin) {
  __shared__ float qs0[64], qs1[64], qs2[64], qw[64];  // SoA query records
  const int lane = threadIdx.x & 63;
  const int w = blockIdx.x * 4 + (threadIdx.x >> 6);  // 0..2047
  const int b = w >> 10;
  const int rem = w & 1023;
  const int tch = rem & (TCH - 1);   // varies across block's 4 waves
  const int qg = rem >> 4;           // uniform across block (4 | TCH)

  // Gather this block's query group directly from pred[idx] (L2-hot).
  if (threadIdx.x < 64) {
    int s = qg * 64 + threadIdx.x;
    int i = idx[s];
    const float* p = pred + ((size_t)b * N + (size_t)i) * 3;
    float x = p[0], y = p[1], z = p[2];
    qs0[threadIdx.x] = -2.0f * x;
    qs1[threadIdx.x] = -2.0f * y;
    qs2[threadIdx.x] = -2.0f * z;
    qw[threadIdx.x] = x * x + y * y + z * z;
  }

  // Stage this lane's 32 targets as 16 float2-pairs (pk_fma operands).
  const float* tb = target + ((size_t)b * M + (size_t)tch * WT) * 3;
  vf2 t0p[16], t1p[16], t2p[16], ty2p[16];
#pragma unroll
  for (int p = 0; p < 16; ++p) {
    int mA = (2 * p) * 64 + lane;
    int mB = (2 * p + 1) * 64 + lane;
    float ax = tb[3 * mA], ay = tb[3 * mA + 1], az = tb[3 * mA + 2];
    float bx = tb[3 * mB], by = tb[3 * mB + 1], bz = tb[3 * mB + 2];
    t0p[p] = vf2{ax, bx};
    t1p[p] = vf2{ay, by};
    t2p[p] = vf2{az, bz};
    ty2p[p] = vf2{fmaf(ax, ax, fmaf(ay, ay, az * az)),
                  fmaf(bx, bx, fmaf(by, by, bz * bz))};
  }
  __syncthreads();

  const float qx2_home = qw[lane];        // own |x|^2, applied at the end
  const int rot = ((lane + 1) & 63) * 4;  // bpermute byte-addr: pull lane+1
  float mm = INFINITY;                    // traveling min of (|y|^2 - 2x.y)
  int qoff = lane;                        // query slot this lane handles now

  for (int step = 0; step < 64; ++step) {
    // Conflict-free SoA reads (4B stride -> 2 lanes/bank = free).
    vf2 q0 = vf2{qs0[qoff], qs0[qoff]};
    vf2 q1 = vf2{qs1[qoff], qs1[qoff]};
    vf2 q2 = vf2{qs2[qoff], qs2[qoff]};
    float m0 = mm, m1 = INFINITY;
#pragma unroll
    for (int p = 0; p < 16; p += 2) {
      vf2 s = __builtin_elementwise_fma(q0, t0p[p], ty2p[p]);
      s = __builtin_elementwise_fma(q1, t1p[p], s);
      s = __builtin_elementwise_fma(q2, t2p[p], s);
      m0 = fminf(fminf(s.x, s.y), m0);  // v_min3_f32
      vf2 u = __builtin_elementwise_fma(q0, t0p[p + 1], ty2p[p + 1]);
      u = __builtin_elementwise_fma(q1, t1p[p + 1], u);
      u = __builtin_elementwise_fma(q2, t2p[p + 1], u);
      m1 = fminf(fminf(u.x, u.y), m1);
    }
    mm = fminf(m0, m1);
    // Traveling min follows its query to the previous lane.
    mm = __int_as_float(__builtin_amdgcn_ds_bpermute(rot, __float_as_int(mm)));
    qoff = (qoff + 1) & 63;
  }
  // After 64 rotations the own query's complete min is back home.
  const int q = b * S + qg * 64 + lane;
  atomicMin(&wsmin[q], __float_as_uint(fmaxf(qx2_home + mm, 0.0f)));
}

__global__ __launch_bounds__(1024) void chamfer_finish(
    const unsigned* __restrict__ wsmin, float* __restrict__ out) {
  __shared__ float red[16];
  float sum = 0.0f;
  for (int q = threadIdx.x; q < QTOT; q += 1024)
    sum += sqrtf(__uint_as_float(wsmin[q]));
#pragma unroll
  for (int off = 32; off > 0; off >>= 1)
    sum += __shfl_down(sum, off, 64);
  int wv = threadIdx.x >> 6;
  if ((threadIdx.x & 63) == 0) red[wv] = sum;
  __syncthreads();
  if (threadIdx.x == 0) {
    float t = 0.0f;
#pragma unroll
    for (int i = 0; i < 16; ++i) t += red[i];
    out[0] = t / (float)QTOT;
  }
}

extern "C" void kernel_launch(void* const* d_in, const int* in_sizes, int n_in,
                              void* d_out, int out_size, void* d_ws, size_t ws_size,
                              hipStream_t stream) {
  const float* pred = (const float*)d_in[0];
  const float* target = (const float*)d_in[1];
  const int* idx = (const int*)d_in[2];
  unsigned* wsmin = (unsigned*)d_ws;

  hipMemsetAsync(wsmin, 0x7F, QTOT * sizeof(unsigned), stream);
  chamfer_main<<<BLOCKS, 256, 0, stream>>>(pred, target, idx, wsmin);
  chamfer_finish<<<1, 1024, 0, stream>>>(wsmin, (float*)d_out);
}